// Round 2
// baseline (209.472 us; speedup 1.0000x reference)
//
#include <hip/hip_runtime.h>
#include <hip/hip_bf16.h>
#include <math.h>

#define BB 32
#define SS 20
#define LL 50
#define NN 40000
#define DD 64
#define IL 4   // n-values per thread in score kernel

// Output layout (flat f32): scores (B,S,N) | hu (B,D) | hc (B,S,D) | attn (B,S,N)
#define OFF_SCORES 0
#define OFF_HU     (BB * SS * NN)                 // 25,600,000
#define OFF_HC     (OFF_HU + BB * DD)             // 25,602,048
#define OFF_ATTN   (OFF_HC + BB * SS * DD)        // 25,643,008

// ---------------------------------------------------------------------------
// Kernel A: per-batch prep. One block per b, 256 threads (4 waves).
// Computes hu[b][64] and hc[b][20][64], writes them into d_out.
// ---------------------------------------------------------------------------
__global__ __launch_bounds__(256) void prep_kernel(
    const int* __restrict__ user_ids,
    const int* __restrict__ sess_item,
    const int* __restrict__ rcnt_item,
    const float* __restrict__ item_emb,
    const float* __restrict__ user_emb,
    const float* __restrict__ user_emb2,
    const float* __restrict__ ue_w1,
    const float* __restrict__ ue_b1,
    const float* __restrict__ ue_w2,
    const float* __restrict__ ue_b2,
    const float* __restrict__ uenc_w,
    const float* __restrict__ uenc_b,
    const float* __restrict__ pred_w,
    const float* __restrict__ pred_b,
    float* __restrict__ out)
{
    const int b    = blockIdx.x;
    const int tid  = threadIdx.x;
    const int lane = tid & 63;
    const int wv   = tid >> 6;

    __shared__ float uemb_s[DD];
    __shared__ float u2_s[DD];
    __shared__ float hs_s[LL][DD];
    __shared__ float wraw_s[LL];
    __shared__ float wn_s[LL];
    __shared__ float part_s[4][DD];
    __shared__ float hr_s[DD];
    __shared__ float e_s[SS][DD + 1];   // +1 pad: lanes index rows -> avoid bank conflicts
    __shared__ float a_tmp[4][SS];

    // ---- phase 1: gather embeddings into LDS ----
    const int uid = user_ids[b];
    if (tid < DD) {
        uemb_s[tid] = user_emb[(size_t)uid * DD + tid];
        u2_s[tid]   = user_emb2[(size_t)uid * DD + tid];
    }
    for (int t = tid; t < LL * DD; t += 256) {
        int l = t >> 6, d = t & 63;
        int idx = rcnt_item[b * LL + l];
        hs_s[l][d] = item_emb[(size_t)idx * DD + d];
    }
    for (int t = tid; t < SS * DD; t += 256) {
        int s = t >> 6, d = t & 63;
        int idx = sess_item[b * SS + s];
        e_s[s][d] = item_emb[(size_t)idx * DD + d];
    }
    __syncthreads();

    // ---- phase 2: attention MLP, w_l raw logits. lane j = hidden unit. ----
    float pu = 0.f;
    #pragma unroll 8
    for (int i = 0; i < DD; ++i) pu += uemb_s[i] * ue_w1[i * DD + lane];
    const float b1j = ue_b1[lane];
    const float w2j = ue_w2[lane];
    const float b2  = ue_b2[0];
    for (int l = wv; l < LL; l += 4) {
        float acc = pu + b1j;
        #pragma unroll 8
        for (int i = 0; i < DD; ++i) acc += hs_s[l][i] * ue_w1[(DD + i) * DD + lane];
        acc = fmaxf(acc, 0.f);
        float contrib = acc * w2j;
        #pragma unroll
        for (int off = 32; off; off >>= 1) contrib += __shfl_xor(contrib, off);
        if (lane == 0) wraw_s[l] = contrib + b2;
    }
    __syncthreads();

    // ---- phase 3: masked softmax over L (wave 0) ----
    if (wv == 0) {
        float x = (lane < LL) ? wraw_s[lane] : -INFINITY;
        float m = x;
        #pragma unroll
        for (int off = 32; off; off >>= 1) m = fmaxf(m, __shfl_xor(m, off));
        float maskl = (lane < LL && rcnt_item[b * LL + lane] != 0) ? 1.f : 0.f;
        float e = (lane < LL) ? (__expf(x - m) + 1e-10f) * maskl : 0.f;
        float sum = e;
        #pragma unroll
        for (int off = 32; off; off >>= 1) sum += __shfl_xor(sum, off);
        if (lane < LL) wn_s[lane] = e / sum;
    }
    __syncthreads();

    // ---- phase 4: hr = sum_l wn_l * hs_l ----
    {
        float p = 0.f;
        for (int l = wv; l < LL; l += 4) p += wn_s[l] * hs_s[l][lane];
        part_s[wv][lane] = p;
    }
    __syncthreads();
    if (wv == 0) hr_s[lane] = part_s[0][lane] + part_s[1][lane] + part_s[2][lane] + part_s[3][lane];
    __syncthreads();

    // ---- phase 5: hu = [u2, hr] @ uenc_w + uenc_b ----
    {
        float p = 0.f;
        for (int i = wv * 32; i < wv * 32 + 32; ++i) {
            float c = (i < DD) ? u2_s[i] : hr_s[i - DD];
            p += c * uenc_w[i * DD + lane];
        }
        part_s[wv][lane] = p;
    }
    __syncthreads();
    if (wv == 0) {
        float hu = uenc_b[lane] + part_s[0][lane] + part_s[1][lane] + part_s[2][lane] + part_s[3][lane];
        out[OFF_HU + b * DD + lane] = hu;
    }

    // ---- phase 6: session self-attention -> hc ----
    for (int s = wv; s < SS; s += 4) {
        const int t = lane;
        float lt = -INFINITY;
        float maskt = 0.f;
        if (t < SS) {
            float dot = 0.f;
            #pragma unroll 8
            for (int d = 0; d < DD; ++d) dot += e_s[s][d] * e_s[t][d];
            lt = dot * 0.125f;
            maskt = (sess_item[b * SS + t] != 0) ? 1.f : 0.f;
        }
        float srow = (sess_item[b * SS + s] != 0) ? 1.f : 0.f;
        float m = lt;
        #pragma unroll
        for (int off = 32; off; off >>= 1) m = fmaxf(m, __shfl_xor(m, off));
        float e = (t < SS) ? (__expf(lt - m) + 1e-10f) * (maskt * srow) : 0.f;
        float sum = e;
        #pragma unroll
        for (int off = 32; off; off >>= 1) sum += __shfl_xor(sum, off);
        if (t < SS) a_tmp[wv][t] = e / sum;
        __syncthreads();
        float hc = 0.f;
        #pragma unroll
        for (int tt = 0; tt < SS; ++tt) hc += a_tmp[wv][tt] * e_s[tt][lane];
        out[OFF_HC + (size_t)(b * SS + s) * DD + lane] = hc;
        __syncthreads();
    }
}

// ---------------------------------------------------------------------------
// Kernel B: scores + attn over (B,S,N). IL=4 n-values per thread: the 22
// comb rows (hc[0..19], hu, wv) are read from LDS ONCE per chunk and reused
// for 4 independent vemb register streams -> FMA-bound, LDS traffic /4.
// ---------------------------------------------------------------------------
__global__ __launch_bounds__(256) void score_kernel(
    const int* __restrict__ items,
    const float* __restrict__ item_emb,
    const float* __restrict__ pred_w,
    const float* __restrict__ pred_b,
    float* __restrict__ out)
{
    const int b    = blockIdx.y;
    const int tid  = threadIdx.x;
    const int base = blockIdx.x * (256 * IL);

    // rows 0..19 = hc[b][s], row 20 = hu[b], row 21 = pred_w[2D..3D) (wv)
    __shared__ __align__(16) float comb_s[22 * DD];
    __shared__ float hcwc_s[SS];
    __shared__ float c0_s;

    for (int t = tid; t < SS * DD; t += 256) comb_s[t] = out[OFF_HC + b * SS * DD + t];
    if (tid < DD) {
        comb_s[20 * DD + tid] = out[OFF_HU + b * DD + tid];
    } else if (tid < 2 * DD) {
        comb_s[21 * DD + (tid - DD)] = pred_w[2 * DD + (tid - DD)];
    }
    __syncthreads();

    // c0 = hu . wu + pred_b  (wave 0); hcwc_s[s] = hc[s] . wc  (all waves)
    if (tid < 64) {
        float p = comb_s[20 * DD + tid] * pred_w[tid];
        #pragma unroll
        for (int off = 32; off; off >>= 1) p += __shfl_xor(p, off);
        if (tid == 0) c0_s = p + pred_b[0];
    }
    {
        const int wvv = tid >> 6, lane = tid & 63;
        for (int s = wvv; s < SS; s += 4) {
            float p = comb_s[s * DD + lane] * pred_w[DD + lane];
            #pragma unroll
            for (int off = 32; off; off >>= 1) p += __shfl_xor(p, off);
            if (lane == 0) hcwc_s[s] = p;
        }
    }
    __syncthreads();

    // ---- per-thread n set: n_i = base + i*256 + tid (coalesced stores) ----
    int   nv[IL];
    bool  valid[IL];
    const float4* vrow[IL];
    #pragma unroll
    for (int i = 0; i < IL; ++i) {
        int ni = base + i * 256 + tid;
        valid[i] = (ni < NN);
        int nl = valid[i] ? ni : (NN - 1);
        int idx = items[b * NN + nl];
        vrow[i] = (const float4*)(item_emb + (size_t)idx * DD);
        nv[i] = ni;
    }

    float acc[IL][22];
    #pragma unroll
    for (int i = 0; i < IL; ++i)
        #pragma unroll
        for (int r = 0; r < 22; ++r) acc[i][r] = 0.f;

    const float4* __restrict__ comb4 = (const float4*)comb_s;
    #pragma unroll 2
    for (int c = 0; c < 16; ++c) {
        float4 v0 = vrow[0][c];
        float4 v1 = vrow[1][c];
        float4 v2 = vrow[2][c];
        float4 v3 = vrow[3][c];
        #pragma unroll
        for (int r = 0; r < 22; ++r) {
            const float4 h = comb4[r * 16 + c];
            acc[0][r] += v0.x * h.x + v0.y * h.y + v0.z * h.z + v0.w * h.w;
            acc[1][r] += v1.x * h.x + v1.y * h.y + v1.z * h.z + v1.w * h.w;
            acc[2][r] += v2.x * h.x + v2.y * h.y + v2.z * h.z + v2.w * h.w;
            acc[3][r] += v3.x * h.x + v3.y * h.y + v3.z * h.z + v3.w * h.w;
        }
    }

    // ---- epilogue: sigmoid blend + streaming stores ----
    #pragma unroll
    for (int i = 0; i < IL; ++i) {
        if (!valid[i]) continue;
        const float huv  = acc[i][20];
        const float gb   = c0_s + acc[i][21];   // c0 + v.wv
        float* sc_out = out + OFF_SCORES + (size_t)b * SS * NN + nv[i];
        float* at_out = out + OFF_ATTN   + (size_t)b * SS * NN + nv[i];
        #pragma unroll
        for (int s = 0; s < SS; ++s) {
            float g    = gb + hcwc_s[s];
            float attn = 1.f / (1.f + __expf(-g));
            float scv  = attn * huv + (1.f - attn) * acc[i][s];
            __builtin_nontemporal_store(scv,  sc_out + (size_t)s * NN);
            __builtin_nontemporal_store(attn, at_out + (size_t)s * NN);
        }
    }
}

extern "C" void kernel_launch(void* const* d_in, const int* in_sizes, int n_in,
                              void* d_out, int out_size, void* d_ws, size_t ws_size,
                              hipStream_t stream) {
    const int*   user_ids  = (const int*)d_in[0];
    const int*   sess_item = (const int*)d_in[1];
    const int*   rcnt_item = (const int*)d_in[2];
    const int*   items     = (const int*)d_in[3];
    const float* item_emb  = (const float*)d_in[4];
    const float* user_emb  = (const float*)d_in[5];
    const float* user_emb2 = (const float*)d_in[6];
    const float* ue_w1     = (const float*)d_in[7];
    const float* ue_b1     = (const float*)d_in[8];
    const float* ue_w2     = (const float*)d_in[9];
    const float* ue_b2     = (const float*)d_in[10];
    const float* uenc_w    = (const float*)d_in[11];
    const float* uenc_b    = (const float*)d_in[12];
    const float* pred_w    = (const float*)d_in[13];
    const float* pred_b    = (const float*)d_in[14];
    float* out = (float*)d_out;

    hipLaunchKernelGGL(prep_kernel, dim3(BB), dim3(256), 0, stream,
                       user_ids, sess_item, rcnt_item, item_emb, user_emb, user_emb2,
                       ue_w1, ue_b1, ue_w2, ue_b2, uenc_w, uenc_b, pred_w, pred_b, out);

    const int nblk = (NN + 256 * IL - 1) / (256 * IL);
    hipLaunchKernelGGL(score_kernel, dim3(nblk, BB), dim3(256), 0, stream,
                       items, item_emb, pred_w, pred_b, out);
}

// Round 4
// 149.237 us; speedup vs baseline: 1.4036x; 1.4036x over previous
//
#include <hip/hip_runtime.h>
#include <hip/hip_bf16.h>
#include <math.h>

#define BB 32
#define SS 20
#define LL 50
#define NN 40000
#define DD 64

// Output layout (flat f32): scores (B,S,N) | hu (B,D) | hc (B,S,D) | attn (B,S,N)
#define OFF_SCORES 0
#define OFF_HU     (BB * SS * NN)                 // 25,600,000
#define OFF_HC     (OFF_HU + BB * DD)             // 25,602,048
#define OFF_ATTN   (OFF_HC + BB * SS * DD)        // 25,643,008

// Constant-address-space cast (CK pattern): uniform loads through here are
// selected as s_load_* (SMEM pipe, SGPR destinations).
#define AS4 __attribute__((address_space(4)))
typedef const AS4 float cfloat;

// ---------------------------------------------------------------------------
// Kernel A: per-batch prep. One block per b, 256 threads (4 waves).
// Computes hu[b][64] and hc[b][20][64], writes them into d_out.
// ---------------------------------------------------------------------------
__global__ __launch_bounds__(256) void prep_kernel(
    const int* __restrict__ user_ids,
    const int* __restrict__ sess_item,
    const int* __restrict__ rcnt_item,
    const float* __restrict__ item_emb,
    const float* __restrict__ user_emb,
    const float* __restrict__ user_emb2,
    const float* __restrict__ ue_w1,
    const float* __restrict__ ue_b1,
    const float* __restrict__ ue_w2,
    const float* __restrict__ ue_b2,
    const float* __restrict__ uenc_w,
    const float* __restrict__ uenc_b,
    const float* __restrict__ pred_w,
    const float* __restrict__ pred_b,
    float* __restrict__ out)
{
    const int b    = blockIdx.x;
    const int tid  = threadIdx.x;
    const int lane = tid & 63;
    const int wv   = tid >> 6;

    __shared__ float uemb_s[DD];
    __shared__ float u2_s[DD];
    __shared__ float hs_s[LL][DD];
    __shared__ float wraw_s[LL];
    __shared__ float wn_s[LL];
    __shared__ float part_s[4][DD];
    __shared__ float hr_s[DD];
    __shared__ float e_s[SS][DD + 1];
    __shared__ float a_tmp[4][SS];

    // ---- phase 1: gather embeddings into LDS ----
    const int uid = user_ids[b];
    if (tid < DD) {
        uemb_s[tid] = user_emb[(size_t)uid * DD + tid];
        u2_s[tid]   = user_emb2[(size_t)uid * DD + tid];
    }
    for (int t = tid; t < LL * DD; t += 256) {
        int l = t >> 6, d = t & 63;
        int idx = rcnt_item[b * LL + l];
        hs_s[l][d] = item_emb[(size_t)idx * DD + d];
    }
    for (int t = tid; t < SS * DD; t += 256) {
        int s = t >> 6, d = t & 63;
        int idx = sess_item[b * SS + s];
        e_s[s][d] = item_emb[(size_t)idx * DD + d];
    }
    __syncthreads();

    // ---- phase 2: attention MLP, w_l raw logits. lane j = hidden unit. ----
    float pu = 0.f;
    #pragma unroll 8
    for (int i = 0; i < DD; ++i) pu += uemb_s[i] * ue_w1[i * DD + lane];
    const float b1j = ue_b1[lane];
    const float w2j = ue_w2[lane];
    const float b2  = ue_b2[0];
    for (int l = wv; l < LL; l += 4) {
        float acc = pu + b1j;
        #pragma unroll 8
        for (int i = 0; i < DD; ++i) acc += hs_s[l][i] * ue_w1[(DD + i) * DD + lane];
        acc = fmaxf(acc, 0.f);
        float contrib = acc * w2j;
        #pragma unroll
        for (int off = 32; off; off >>= 1) contrib += __shfl_xor(contrib, off);
        if (lane == 0) wraw_s[l] = contrib + b2;
    }
    __syncthreads();

    // ---- phase 3: masked softmax over L (wave 0) ----
    if (wv == 0) {
        float x = (lane < LL) ? wraw_s[lane] : -INFINITY;
        float m = x;
        #pragma unroll
        for (int off = 32; off; off >>= 1) m = fmaxf(m, __shfl_xor(m, off));
        float maskl = (lane < LL && rcnt_item[b * LL + lane] != 0) ? 1.f : 0.f;
        float e = (lane < LL) ? (__expf(x - m) + 1e-10f) * maskl : 0.f;
        float sum = e;
        #pragma unroll
        for (int off = 32; off; off >>= 1) sum += __shfl_xor(sum, off);
        if (lane < LL) wn_s[lane] = e / sum;
    }
    __syncthreads();

    // ---- phase 4: hr = sum_l wn_l * hs_l ----
    {
        float p = 0.f;
        for (int l = wv; l < LL; l += 4) p += wn_s[l] * hs_s[l][lane];
        part_s[wv][lane] = p;
    }
    __syncthreads();
    if (wv == 0) hr_s[lane] = part_s[0][lane] + part_s[1][lane] + part_s[2][lane] + part_s[3][lane];
    __syncthreads();

    // ---- phase 5: hu = [u2, hr] @ uenc_w + uenc_b ----
    {
        float p = 0.f;
        for (int i = wv * 32; i < wv * 32 + 32; ++i) {
            float c = (i < DD) ? u2_s[i] : hr_s[i - DD];
            p += c * uenc_w[i * DD + lane];
        }
        part_s[wv][lane] = p;
    }
    __syncthreads();
    if (wv == 0) {
        float hu = uenc_b[lane] + part_s[0][lane] + part_s[1][lane] + part_s[2][lane] + part_s[3][lane];
        out[OFF_HU + b * DD + lane] = hu;
    }

    // ---- phase 6: session self-attention -> hc ----
    for (int s = wv; s < SS; s += 4) {
        const int t = lane;
        float lt = -INFINITY;
        float maskt = 0.f;
        if (t < SS) {
            float dot = 0.f;
            #pragma unroll 8
            for (int d = 0; d < DD; ++d) dot += e_s[s][d] * e_s[t][d];
            lt = dot * 0.125f;
            maskt = (sess_item[b * SS + t] != 0) ? 1.f : 0.f;
        }
        float srow = (sess_item[b * SS + s] != 0) ? 1.f : 0.f;
        float m = lt;
        #pragma unroll
        for (int off = 32; off; off >>= 1) m = fmaxf(m, __shfl_xor(m, off));
        float e = (t < SS) ? (__expf(lt - m) + 1e-10f) * (maskt * srow) : 0.f;
        float sum = e;
        #pragma unroll
        for (int off = 32; off; off >>= 1) sum += __shfl_xor(sum, off);
        if (t < SS) a_tmp[wv][t] = e / sum;
        __syncthreads();
        float hc = 0.f;
        #pragma unroll
        for (int tt = 0; tt < SS; ++tt) hc += a_tmp[wv][tt] * e_s[tt][lane];
        out[OFF_HC + (size_t)(b * SS + s) * DD + lane] = hc;
        __syncthreads();
    }
}

// ---------------------------------------------------------------------------
// Kernel B: scores + attn over (B,S,N). One thread per n. vemb row fully
// register-resident (64 VGPR, one contiguous 256B pass). The comb rows
// (hc[0..19], hu, wv) are wave-uniform -> read through the CONSTANT address
// space so the compiler emits s_load_* into SGPRs (SMEM pipe). Inner loop is
// v_fmac_f32 v,s,v: zero LDS traffic, zero per-lane VMEM for comb.
// (Round-1 was LDS-pipe-bound: 352 ds_read_b128/wave = 4224 cyc vs 2816 VALU.)
// ---------------------------------------------------------------------------
__global__ __launch_bounds__(256, 4) void score_kernel(
    const int* __restrict__ items,
    const float* __restrict__ item_emb,
    const float* __restrict__ pred_w,
    const float* __restrict__ pred_b,
    float* __restrict__ out)
{
    const int b   = blockIdx.y;
    const int tid = threadIdx.x;
    const int n   = blockIdx.x * 256 + tid;

    __shared__ float hcwc_s[SS];
    __shared__ float c0_s;

    // c0 = hu . wu + pred_b  (wave 0); hcwc_s[s] = hc[s] . wc  (all waves)
    if (tid < 64) {
        float p = out[OFF_HU + b * DD + tid] * pred_w[tid];
        #pragma unroll
        for (int off = 32; off; off >>= 1) p += __shfl_xor(p, off);
        if (tid == 0) c0_s = p + pred_b[0];
    }
    {
        const int wvv = tid >> 6, lane = tid & 63;
        for (int s = wvv; s < SS; s += 4) {
            float p = out[OFF_HC + ((size_t)b * SS + s) * DD + lane] * pred_w[DD + lane];
            #pragma unroll
            for (int off = 32; off; off >>= 1) p += __shfl_xor(p, off);
            if (lane == 0) hcwc_s[s] = p;
        }
    }
    __syncthreads();

    const bool valid = (n < NN);
    const int  nl    = valid ? n : (NN - 1);
    const int  idx   = items[b * NN + nl];

    // full vemb row -> 16 float4 = 64 VGPRs, contiguous (good line utilization)
    float4 v[16];
    {
        const float4* __restrict__ vrow4 = (const float4*)(item_emb + (size_t)idx * DD);
        #pragma unroll
        for (int c = 0; c < 16; ++c) v[c] = vrow4[c];
    }

    // wave-uniform comb pointers through the constant address space
    cfloat* hcP = (cfloat*)(uintptr_t)(out + OFF_HC + (size_t)b * SS * DD);
    cfloat* huP = (cfloat*)(uintptr_t)(out + OFF_HU + (size_t)b * DD);
    cfloat* wvP = (cfloat*)(uintptr_t)(pred_w + 2 * DD);

    float acc[22];
    #pragma unroll
    for (int r = 0; r < 22; ++r) {
        cfloat* crow = (r < 20) ? (hcP + r * DD) : (r == 20 ? huP : wvP);
        float a0 = 0.f, a1 = 0.f, a2 = 0.f, a3 = 0.f;
        #pragma unroll
        for (int c = 0; c < 4; ++c) {
            const float4 x0 = v[4 * 0 + c];
            const float4 x1 = v[4 * 1 + c];
            const float4 x2 = v[4 * 2 + c];
            const float4 x3 = v[4 * 3 + c];
            const int d0 = 16 * 0 + 4 * c, d1 = 16 * 1 + 4 * c,
                      d2 = 16 * 2 + 4 * c, d3 = 16 * 3 + 4 * c;
            a0 += x0.x * crow[d0 + 0] + x0.y * crow[d0 + 1] + x0.z * crow[d0 + 2] + x0.w * crow[d0 + 3];
            a1 += x1.x * crow[d1 + 0] + x1.y * crow[d1 + 1] + x1.z * crow[d1 + 2] + x1.w * crow[d1 + 3];
            a2 += x2.x * crow[d2 + 0] + x2.y * crow[d2 + 1] + x2.z * crow[d2 + 2] + x2.w * crow[d2 + 3];
            a3 += x3.x * crow[d3 + 0] + x3.y * crow[d3 + 1] + x3.z * crow[d3 + 2] + x3.w * crow[d3 + 3];
        }
        acc[r] = (a0 + a1) + (a2 + a3);
    }

    if (!valid) return;

    const float huv = acc[20];
    const float gb  = c0_s + acc[21];   // c0 + v.wv
    float* sc_out = out + OFF_SCORES + (size_t)b * SS * NN + n;
    float* at_out = out + OFF_ATTN   + (size_t)b * SS * NN + n;

    #pragma unroll
    for (int s = 0; s < SS; ++s) {
        float g    = gb + hcwc_s[s];
        float attn = 1.f / (1.f + __expf(-g));
        float scv  = attn * huv + (1.f - attn) * acc[s];
        __builtin_nontemporal_store(scv,  sc_out + (size_t)s * NN);
        __builtin_nontemporal_store(attn, at_out + (size_t)s * NN);
    }
}

extern "C" void kernel_launch(void* const* d_in, const int* in_sizes, int n_in,
                              void* d_out, int out_size, void* d_ws, size_t ws_size,
                              hipStream_t stream) {
    const int*   user_ids  = (const int*)d_in[0];
    const int*   sess_item = (const int*)d_in[1];
    const int*   rcnt_item = (const int*)d_in[2];
    const int*   items     = (const int*)d_in[3];
    const float* item_emb  = (const float*)d_in[4];
    const float* user_emb  = (const float*)d_in[5];
    const float* user_emb2 = (const float*)d_in[6];
    const float* ue_w1     = (const float*)d_in[7];
    const float* ue_b1     = (const float*)d_in[8];
    const float* ue_w2     = (const float*)d_in[9];
    const float* ue_b2     = (const float*)d_in[10];
    const float* uenc_w    = (const float*)d_in[11];
    const float* uenc_b    = (const float*)d_in[12];
    const float* pred_w    = (const float*)d_in[13];
    const float* pred_b    = (const float*)d_in[14];
    float* out = (float*)d_out;

    hipLaunchKernelGGL(prep_kernel, dim3(BB), dim3(256), 0, stream,
                       user_ids, sess_item, rcnt_item, item_emb, user_emb, user_emb2,
                       ue_w1, ue_b1, ue_w2, ue_b2, uenc_w, uenc_b, pred_w, pred_b, out);

    hipLaunchKernelGGL(score_kernel, dim3((NN + 255) / 256, BB), dim3(256), 0, stream,
                       items, item_emb, pred_w, pred_b, out);
}

// Round 5
// 143.348 us; speedup vs baseline: 1.4613x; 1.0411x over previous
//
#include <hip/hip_runtime.h>
#include <hip/hip_bf16.h>
#include <math.h>

#define BB 32
#define SS 20
#define LL 50
#define NN 40000
#define DD 64
#define TILE_N 512
#define NTILES ((NN + TILE_N - 1) / TILE_N)   // 79

// Output layout (flat f32): scores (B,S,N) | hu (B,D) | hc (B,S,D) | attn (B,S,N)
#define OFF_SCORES 0
#define OFF_HU     (BB * SS * NN)                 // 25,600,000
#define OFF_HC     (OFF_HU + BB * DD)             // 25,602,048
#define OFF_ATTN   (OFF_HC + BB * SS * DD)        // 25,643,008

typedef short short8 __attribute__((ext_vector_type(8)));
typedef float f32x4  __attribute__((ext_vector_type(4)));

__device__ __forceinline__ unsigned short f2bf(float x) {   // RNE f32->bf16
    unsigned u = __float_as_uint(x);
    unsigned r = (u + 0x7fffu + ((u >> 16) & 1u)) >> 16;
    return (unsigned short)r;
}
__device__ __forceinline__ float bf2f(unsigned short h) {
    return __uint_as_float(((unsigned)h) << 16);
}

// ---------------------------------------------------------------------------
// Kernel A: per-batch prep (unchanged). One block per b, 256 threads.
// ---------------------------------------------------------------------------
__global__ __launch_bounds__(256) void prep_kernel(
    const int* __restrict__ user_ids,
    const int* __restrict__ sess_item,
    const int* __restrict__ rcnt_item,
    const float* __restrict__ item_emb,
    const float* __restrict__ user_emb,
    const float* __restrict__ user_emb2,
    const float* __restrict__ ue_w1,
    const float* __restrict__ ue_b1,
    const float* __restrict__ ue_w2,
    const float* __restrict__ ue_b2,
    const float* __restrict__ uenc_w,
    const float* __restrict__ uenc_b,
    const float* __restrict__ pred_w,
    const float* __restrict__ pred_b,
    float* __restrict__ out)
{
    const int b    = blockIdx.x;
    const int tid  = threadIdx.x;
    const int lane = tid & 63;
    const int wv   = tid >> 6;

    __shared__ float uemb_s[DD];
    __shared__ float u2_s[DD];
    __shared__ float hs_s[LL][DD];
    __shared__ float wraw_s[LL];
    __shared__ float wn_s[LL];
    __shared__ float part_s[4][DD];
    __shared__ float hr_s[DD];
    __shared__ float e_s[SS][DD + 1];
    __shared__ float a_tmp[4][SS];

    const int uid = user_ids[b];
    if (tid < DD) {
        uemb_s[tid] = user_emb[(size_t)uid * DD + tid];
        u2_s[tid]   = user_emb2[(size_t)uid * DD + tid];
    }
    for (int t = tid; t < LL * DD; t += 256) {
        int l = t >> 6, d = t & 63;
        int idx = rcnt_item[b * LL + l];
        hs_s[l][d] = item_emb[(size_t)idx * DD + d];
    }
    for (int t = tid; t < SS * DD; t += 256) {
        int s = t >> 6, d = t & 63;
        int idx = sess_item[b * SS + s];
        e_s[s][d] = item_emb[(size_t)idx * DD + d];
    }
    __syncthreads();

    float pu = 0.f;
    #pragma unroll 8
    for (int i = 0; i < DD; ++i) pu += uemb_s[i] * ue_w1[i * DD + lane];
    const float b1j = ue_b1[lane];
    const float w2j = ue_w2[lane];
    const float b2  = ue_b2[0];
    for (int l = wv; l < LL; l += 4) {
        float acc = pu + b1j;
        #pragma unroll 8
        for (int i = 0; i < DD; ++i) acc += hs_s[l][i] * ue_w1[(DD + i) * DD + lane];
        acc = fmaxf(acc, 0.f);
        float contrib = acc * w2j;
        #pragma unroll
        for (int off = 32; off; off >>= 1) contrib += __shfl_xor(contrib, off);
        if (lane == 0) wraw_s[l] = contrib + b2;
    }
    __syncthreads();

    if (wv == 0) {
        float x = (lane < LL) ? wraw_s[lane] : -INFINITY;
        float m = x;
        #pragma unroll
        for (int off = 32; off; off >>= 1) m = fmaxf(m, __shfl_xor(m, off));
        float maskl = (lane < LL && rcnt_item[b * LL + lane] != 0) ? 1.f : 0.f;
        float e = (lane < LL) ? (__expf(x - m) + 1e-10f) * maskl : 0.f;
        float sum = e;
        #pragma unroll
        for (int off = 32; off; off >>= 1) sum += __shfl_xor(sum, off);
        if (lane < LL) wn_s[lane] = e / sum;
    }
    __syncthreads();

    {
        float p = 0.f;
        for (int l = wv; l < LL; l += 4) p += wn_s[l] * hs_s[l][lane];
        part_s[wv][lane] = p;
    }
    __syncthreads();
    if (wv == 0) hr_s[lane] = part_s[0][lane] + part_s[1][lane] + part_s[2][lane] + part_s[3][lane];
    __syncthreads();

    {
        float p = 0.f;
        for (int i = wv * 32; i < wv * 32 + 32; ++i) {
            float c = (i < DD) ? u2_s[i] : hr_s[i - DD];
            p += c * uenc_w[i * DD + lane];
        }
        part_s[wv][lane] = p;
    }
    __syncthreads();
    if (wv == 0) {
        float hu = uenc_b[lane] + part_s[0][lane] + part_s[1][lane] + part_s[2][lane] + part_s[3][lane];
        out[OFF_HU + b * DD + lane] = hu;
    }

    for (int s = wv; s < SS; s += 4) {
        const int t = lane;
        float lt = -INFINITY;
        float maskt = 0.f;
        if (t < SS) {
            float dot = 0.f;
            #pragma unroll 8
            for (int d = 0; d < DD; ++d) dot += e_s[s][d] * e_s[t][d];
            lt = dot * 0.125f;
            maskt = (sess_item[b * SS + t] != 0) ? 1.f : 0.f;
        }
        float srow = (sess_item[b * SS + s] != 0) ? 1.f : 0.f;
        float m = lt;
        #pragma unroll
        for (int off = 32; off; off >>= 1) m = fmaxf(m, __shfl_xor(m, off));
        float e = (t < SS) ? (__expf(lt - m) + 1e-10f) * (maskt * srow) : 0.f;
        float sum = e;
        #pragma unroll
        for (int off = 32; off; off >>= 1) sum += __shfl_xor(sum, off);
        if (t < SS) a_tmp[wv][t] = e / sum;
        __syncthreads();
        float hc = 0.f;
        #pragma unroll
        for (int tt = 0; tt < SS; ++tt) hc += a_tmp[wv][tt] * e_s[tt][lane];
        out[OFF_HC + (size_t)(b * SS + s) * DD + lane] = hc;
        __syncthreads();
    }
}

// ---------------------------------------------------------------------------
// Kernel B (MFMA): per block (b, n-tile of 512): G[32 x 512] = comb . vemb^T
// via mfma_f32_16x16x32_bf16. A = comb rows (hc0..19, hu, wv, pad), hi+lo
// bf16 split, fragment-resident in VGPRs. B = vemb tile staged in LDS as
// bf16 rows padded to 144 B (bank-conflict-free reads). Rows 20/21 of G are
// huv/vwv, redistributed by one __shfl each. Epilogue: sigmoid blend.
// ---------------------------------------------------------------------------
__global__ __launch_bounds__(512) void score_kernel(
    const int* __restrict__ items,
    const float* __restrict__ item_emb,
    const float* __restrict__ pred_w,
    const float* __restrict__ pred_b,
    float* __restrict__ out)
{
    const int b   = blockIdx.y;
    const int tid = threadIdx.x;
    const int n0  = blockIdx.x * TILE_N;

    __shared__ __align__(16) short vlds[TILE_N * 72];  // 512 rows x 144 B (64 bf16 + pad)
    __shared__ float hcwc_s[SS];
    __shared__ float c0_s;

    // ---- prologue: c0 = hu.wu + pred_b (wave 0); hcwc[s] = hc[s].wc ----
    if (tid < 64) {
        float p = out[OFF_HU + b * DD + tid] * pred_w[tid];
        #pragma unroll
        for (int off = 32; off; off >>= 1) p += __shfl_xor(p, off);
        if (tid == 0) c0_s = p + pred_b[0];
    }
    {
        const int wvv = tid >> 6, lane = tid & 63;
        for (int s = wvv; s < SS; s += 8) {
            float p = out[OFF_HC + ((size_t)b * SS + s) * DD + lane] * pred_w[DD + lane];
            #pragma unroll
            for (int off = 32; off; off >>= 1) p += __shfl_xor(p, off);
            if (lane == 0) hcwc_s[s] = p;
        }
    }

    // ---- stage vemb tile -> LDS (bf16, 144B rows, chunk-XOR write order) ----
    {
        int ng  = n0 + tid;
        int nl  = (ng < NN) ? ng : (NN - 1);
        int idx = items[b * NN + nl];
        const float4* __restrict__ vr = (const float4*)(item_emb + (size_t)idx * DD);
        #pragma unroll
        for (int c = 0; c < 8; ++c) {
            int cc = c ^ ((tid >> 3) & 7);
            float4 a = vr[2 * cc], q = vr[2 * cc + 1];
            short8 s8;
            s8[0] = (short)f2bf(a.x); s8[1] = (short)f2bf(a.y);
            s8[2] = (short)f2bf(a.z); s8[3] = (short)f2bf(a.w);
            s8[4] = (short)f2bf(q.x); s8[5] = (short)f2bf(q.y);
            s8[6] = (short)f2bf(q.z); s8[7] = (short)f2bf(q.w);
            *(short8*)&vlds[tid * 72 + cc * 8] = s8;
        }
    }

    // ---- A fragments (comb rows 0..31), hi+lo bf16 split, once per block ----
    const int l  = tid & 63;
    const int lr = l & 15;    // C col / A row within 16-tile
    const int lg = l >> 4;    // k-chunk group
    short8 aHi[2][2], aLo[2][2];
    #pragma unroll
    for (int mt = 0; mt < 2; ++mt) {
        int row = mt * 16 + lr;
        const float* rp = (row < 20) ? (out + OFF_HC + ((size_t)b * SS + row) * DD)
                        : (row == 20) ? (out + OFF_HU + (size_t)b * DD)
                        : (row == 21) ? (pred_w + 2 * DD) : nullptr;
        #pragma unroll
        for (int ks = 0; ks < 2; ++ks) {
            float v[8];
            if (rp) {
                const float4* p4 = (const float4*)(rp + ks * 32 + lg * 8);
                float4 x = p4[0], y = p4[1];
                v[0]=x.x; v[1]=x.y; v[2]=x.z; v[3]=x.w;
                v[4]=y.x; v[5]=y.y; v[6]=y.z; v[7]=y.w;
            } else {
                #pragma unroll
                for (int j = 0; j < 8; ++j) v[j] = 0.f;
            }
            short8 h, lo;
            #pragma unroll
            for (int j = 0; j < 8; ++j) {
                unsigned short hb = f2bf(v[j]);
                h[j]  = (short)hb;
                lo[j] = (short)f2bf(v[j] - bf2f(hb));
            }
            aHi[mt][ks] = h;
            aLo[mt][ks] = lo;
        }
    }

    __syncthreads();

    // per-lane hoisted hcwc values (rows this lane owns in C)
    float hcA[4], hcB[4];
    #pragma unroll
    for (int j = 0; j < 4; ++j) { hcA[j] = hcwc_s[lg * 4 + j]; hcB[j] = hcwc_s[16 + j]; }
    const float c0 = c0_s;

    const int w = tid >> 6;   // wave id: 64-col strip within the tile
    #pragma unroll
    for (int nt = 0; nt < 4; ++nt) {
        const int cb   = w * 64 + nt * 16;
        const int brow = cb + lr;
        short8 b0 = *(const short8*)&vlds[brow * 72 +      lg * 8];
        short8 b1 = *(const short8*)&vlds[brow * 72 + 32 + lg * 8];

        f32x4 acc0 = {0.f, 0.f, 0.f, 0.f};
        f32x4 acc1 = {0.f, 0.f, 0.f, 0.f};
        acc0 = __builtin_amdgcn_mfma_f32_16x16x32_bf16(aHi[0][0], b0, acc0, 0, 0, 0);
        acc0 = __builtin_amdgcn_mfma_f32_16x16x32_bf16(aLo[0][0], b0, acc0, 0, 0, 0);
        acc0 = __builtin_amdgcn_mfma_f32_16x16x32_bf16(aHi[0][1], b1, acc0, 0, 0, 0);
        acc0 = __builtin_amdgcn_mfma_f32_16x16x32_bf16(aLo[0][1], b1, acc0, 0, 0, 0);
        acc1 = __builtin_amdgcn_mfma_f32_16x16x32_bf16(aHi[1][0], b0, acc1, 0, 0, 0);
        acc1 = __builtin_amdgcn_mfma_f32_16x16x32_bf16(aLo[1][0], b0, acc1, 0, 0, 0);
        acc1 = __builtin_amdgcn_mfma_f32_16x16x32_bf16(aHi[1][1], b1, acc1, 0, 0, 0);
        acc1 = __builtin_amdgcn_mfma_f32_16x16x32_bf16(aLo[1][1], b1, acc1, 0, 0, 0);

        // rows 20 (huv) / 21 (vwv) live in regs 0/1 of lanes 16..31
        float huv = __shfl(acc1[0], 16 + lr);
        float vwv = __shfl(acc1[1], 16 + lr);

        const int n = n0 + cb + lr;
        if (n < NN) {
            const float gb = c0 + vwv;
            float* sc = out + OFF_SCORES + (size_t)b * SS * NN + n;
            float* at = out + OFF_ATTN   + (size_t)b * SS * NN + n;
            #pragma unroll
            for (int j = 0; j < 4; ++j) {           // rows lg*4+j (all < 16)
                int s = lg * 4 + j;
                float g    = gb + hcA[j];
                float attn = 1.f / (1.f + __expf(-g));
                float scv  = attn * huv + (1.f - attn) * acc0[j];
                __builtin_nontemporal_store(scv,  sc + (size_t)s * NN);
                __builtin_nontemporal_store(attn, at + (size_t)s * NN);
            }
            if (lg == 0) {                          // rows 16..19 from acc1
                #pragma unroll
                for (int j = 0; j < 4; ++j) {
                    int s = 16 + j;
                    float g    = gb + hcB[j];
                    float attn = 1.f / (1.f + __expf(-g));
                    float scv  = attn * huv + (1.f - attn) * acc1[j];
                    __builtin_nontemporal_store(scv,  sc + (size_t)s * NN);
                    __builtin_nontemporal_store(attn, at + (size_t)s * NN);
                }
            }
        }
    }
}

extern "C" void kernel_launch(void* const* d_in, const int* in_sizes, int n_in,
                              void* d_out, int out_size, void* d_ws, size_t ws_size,
                              hipStream_t stream) {
    const int*   user_ids  = (const int*)d_in[0];
    const int*   sess_item = (const int*)d_in[1];
    const int*   rcnt_item = (const int*)d_in[2];
    const int*   items     = (const int*)d_in[3];
    const float* item_emb  = (const float*)d_in[4];
    const float* user_emb  = (const float*)d_in[5];
    const float* user_emb2 = (const float*)d_in[6];
    const float* ue_w1     = (const float*)d_in[7];
    const float* ue_b1     = (const float*)d_in[8];
    const float* ue_w2     = (const float*)d_in[9];
    const float* ue_b2     = (const float*)d_in[10];
    const float* uenc_w    = (const float*)d_in[11];
    const float* uenc_b    = (const float*)d_in[12];
    const float* pred_w    = (const float*)d_in[13];
    const float* pred_b    = (const float*)d_in[14];
    float* out = (float*)d_out;

    hipLaunchKernelGGL(prep_kernel, dim3(BB), dim3(256), 0, stream,
                       user_ids, sess_item, rcnt_item, item_emb, user_emb, user_emb2,
                       ue_w1, ue_b1, ue_w2, ue_b2, uenc_w, uenc_b, pred_w, pred_b, out);

    hipLaunchKernelGGL(score_kernel, dim3(NTILES, BB), dim3(512), 0, stream,
                       items, item_emb, pred_w, pred_b, out);
}

// Round 7
// 123.420 us; speedup vs baseline: 1.6972x; 1.1615x over previous
//
#include <hip/hip_runtime.h>
#include <hip/hip_bf16.h>
#include <math.h>

#define BB 32
#define SS 20
#define LL 50
#define NN 40000
#define DD 64

// Output layout (flat f32): scores (B,S,N) | hu (B,D) | hc (B,S,D) | attn (B,S,N)
#define OFF_SCORES 0
#define OFF_HU     (BB * SS * NN)                 // 25,600,000
#define OFF_HC     (OFF_HU + BB * DD)             // 25,602,048
#define OFF_ATTN   (OFF_HC + BB * SS * DD)        // 25,643,008

// d_ws: ONLY 32 b x 32 f32 scalars (slots 0..19 hcwc, 24 c0, rest 0) = 4 KB.

typedef short  short8 __attribute__((ext_vector_type(8)));
typedef float  f32x16 __attribute__((ext_vector_type(16)));

__device__ __forceinline__ unsigned short f2bf(float x) {   // RNE f32->bf16
    unsigned u = __float_as_uint(x);
    unsigned r = (u + 0x7fffu + ((u >> 16) & 1u)) >> 16;
    return (unsigned short)r;
}
__device__ __forceinline__ float bf2f(unsigned short h) {
    return __uint_as_float(((unsigned)h) << 16);
}
__device__ __forceinline__ short8 pack8(float4 x, float4 y) {
    short8 r;
    r[0] = (short)f2bf(x.x); r[1] = (short)f2bf(x.y);
    r[2] = (short)f2bf(x.z); r[3] = (short)f2bf(x.w);
    r[4] = (short)f2bf(y.x); r[5] = (short)f2bf(y.y);
    r[6] = (short)f2bf(y.z); r[7] = (short)f2bf(y.w);
    return r;
}

// ---------------------------------------------------------------------------
// Kernel A: per-batch prep. One block per b, 256 threads (4 waves).
// Computes hu, hc (f32, into out) and hcwc[20] + c0 scalars (into ws).
// ---------------------------------------------------------------------------
__global__ __launch_bounds__(256) void prep_kernel(
    const int* __restrict__ user_ids,
    const int* __restrict__ sess_item,
    const int* __restrict__ rcnt_item,
    const float* __restrict__ item_emb,
    const float* __restrict__ user_emb,
    const float* __restrict__ user_emb2,
    const float* __restrict__ ue_w1,
    const float* __restrict__ ue_b1,
    const float* __restrict__ ue_w2,
    const float* __restrict__ ue_b2,
    const float* __restrict__ uenc_w,
    const float* __restrict__ uenc_b,
    const float* __restrict__ pred_w,
    const float* __restrict__ pred_b,
    float* __restrict__ out,
    float* __restrict__ hcwc_ws)
{
    const int b    = blockIdx.x;
    const int tid  = threadIdx.x;
    const int lane = tid & 63;
    const int wv   = tid >> 6;

    __shared__ float uemb_s[DD];
    __shared__ float u2_s[DD];
    __shared__ float hs_s[LL][DD];
    __shared__ float wraw_s[LL];
    __shared__ float wn_s[LL];
    __shared__ float part_s[4][DD];
    __shared__ float hr_s[DD];
    __shared__ float e_s[SS][DD + 1];
    __shared__ float a_tmp[4][SS];
    __shared__ float hc_s[SS][DD];
    __shared__ float hu_s[DD];

    const int uid = user_ids[b];
    if (tid < DD) {
        uemb_s[tid] = user_emb[(size_t)uid * DD + tid];
        u2_s[tid]   = user_emb2[(size_t)uid * DD + tid];
    }
    for (int t = tid; t < LL * DD; t += 256) {
        int l = t >> 6, d = t & 63;
        int idx = rcnt_item[b * LL + l];
        hs_s[l][d] = item_emb[(size_t)idx * DD + d];
    }
    for (int t = tid; t < SS * DD; t += 256) {
        int s = t >> 6, d = t & 63;
        int idx = sess_item[b * SS + s];
        e_s[s][d] = item_emb[(size_t)idx * DD + d];
    }
    __syncthreads();

    float pu = 0.f;
    #pragma unroll 8
    for (int i = 0; i < DD; ++i) pu += uemb_s[i] * ue_w1[i * DD + lane];
    const float b1j = ue_b1[lane];
    const float w2j = ue_w2[lane];
    const float b2  = ue_b2[0];
    for (int l = wv; l < LL; l += 4) {
        float acc = pu + b1j;
        #pragma unroll 8
        for (int i = 0; i < DD; ++i) acc += hs_s[l][i] * ue_w1[(DD + i) * DD + lane];
        acc = fmaxf(acc, 0.f);
        float contrib = acc * w2j;
        #pragma unroll
        for (int off = 32; off; off >>= 1) contrib += __shfl_xor(contrib, off);
        if (lane == 0) wraw_s[l] = contrib + b2;
    }
    __syncthreads();

    if (wv == 0) {
        float x = (lane < LL) ? wraw_s[lane] : -INFINITY;
        float m = x;
        #pragma unroll
        for (int off = 32; off; off >>= 1) m = fmaxf(m, __shfl_xor(m, off));
        float maskl = (lane < LL && rcnt_item[b * LL + lane] != 0) ? 1.f : 0.f;
        float e = (lane < LL) ? (__expf(x - m) + 1e-10f) * maskl : 0.f;
        float sum = e;
        #pragma unroll
        for (int off = 32; off; off >>= 1) sum += __shfl_xor(sum, off);
        if (lane < LL) wn_s[lane] = e / sum;
    }
    __syncthreads();

    {
        float p = 0.f;
        for (int l = wv; l < LL; l += 4) p += wn_s[l] * hs_s[l][lane];
        part_s[wv][lane] = p;
    }
    __syncthreads();
    if (wv == 0) hr_s[lane] = part_s[0][lane] + part_s[1][lane] + part_s[2][lane] + part_s[3][lane];
    __syncthreads();

    {
        float p = 0.f;
        for (int i = wv * 32; i < wv * 32 + 32; ++i) {
            float c = (i < DD) ? u2_s[i] : hr_s[i - DD];
            p += c * uenc_w[i * DD + lane];
        }
        part_s[wv][lane] = p;
    }
    __syncthreads();
    if (wv == 0) {
        float hu = uenc_b[lane] + part_s[0][lane] + part_s[1][lane] + part_s[2][lane] + part_s[3][lane];
        hu_s[lane] = hu;
        out[OFF_HU + b * DD + lane] = hu;
    }
    __syncthreads();

    for (int s = wv; s < SS; s += 4) {
        const int t = lane;
        float lt = -INFINITY;
        float maskt = 0.f;
        if (t < SS) {
            float dot = 0.f;
            #pragma unroll 8
            for (int d = 0; d < DD; ++d) dot += e_s[s][d] * e_s[t][d];
            lt = dot * 0.125f;
            maskt = (sess_item[b * SS + t] != 0) ? 1.f : 0.f;
        }
        float srow = (sess_item[b * SS + s] != 0) ? 1.f : 0.f;
        float m = lt;
        #pragma unroll
        for (int off = 32; off; off >>= 1) m = fmaxf(m, __shfl_xor(m, off));
        float e = (t < SS) ? (__expf(lt - m) + 1e-10f) * (maskt * srow) : 0.f;
        float sum = e;
        #pragma unroll
        for (int off = 32; off; off >>= 1) sum += __shfl_xor(sum, off);
        if (t < SS) a_tmp[wv][t] = e / sum;
        __syncthreads();
        float hc = 0.f;
        #pragma unroll
        for (int tt = 0; tt < SS; ++tt) hc += a_tmp[wv][tt] * e_s[tt][lane];
        hc_s[s][lane] = hc;
        out[OFF_HC + (size_t)(b * SS + s) * DD + lane] = hc;
        __syncthreads();
    }

    // ---- phase 7: scalars for score kernel ----
    for (int s = wv; s < SS; s += 4) {                 // hcwc[s] = hc[s].wc
        float p = hc_s[s][lane] * pred_w[DD + lane];
        #pragma unroll
        for (int off = 32; off; off >>= 1) p += __shfl_xor(p, off);
        if (lane == 0) hcwc_ws[b * 32 + s] = p;
    }
    if (wv == 1) {                                      // c0 -> slot 24
        float p = hu_s[lane] * pred_w[lane];
        #pragma unroll
        for (int off = 32; off; off >>= 1) p += __shfl_xor(p, off);
        if (lane == 0) hcwc_ws[b * 32 + 24] = p + pred_b[0];
    }
    if (tid < 11) {                                     // zero 20..23, 25..31
        int sl = (tid < 4) ? (20 + tid) : (21 + tid);
        hcwc_ws[b * 32 + sl] = 0.f;
    }
}

// ---------------------------------------------------------------------------
// Kernel B (MFMA): barrier-free, LDS-free, 4 KB ws. Wave = 64-col strip of
// one batch, 2 tiles of 32 cols. G[32 x 32] = comb . vemb^T via
// mfma_f32_32x32x16_bf16, K=64 (4 k-steps). A = comb rows (hc0..19, hu, wv,
// zero-pad), hi+lo bf16 split (A exact), built once per wave from the f32
// rows in `out`. B = vemb rows converted f32->bf16 in-register (no table).
// C layout: col=lane&31, row=(reg&3)+8*(reg>>2)+4*(lane>>5). Rows 20/21 of G
// are huv/vwv (regs 8/9, hi half), redistributed by one __shfl each.
// ---------------------------------------------------------------------------
__global__ __launch_bounds__(256) void score_kernel(
    const int* __restrict__ items,
    const float* __restrict__ item_emb,
    const float* __restrict__ pred_w,
    const float* __restrict__ hcwc_ws,
    float* __restrict__ out)
{
    const int tid   = threadIdx.x;
    const int lane  = tid & 63;
    const int wv    = tid >> 6;
    const int b     = blockIdx.y;
    const int strip = blockIdx.x * 4 + wv;          // 64-column strip
    if (strip >= NN / 64) return;                   // wave-uniform exit
    const int n0 = strip * 64;
    const int c  = lane & 31;
    const int hi = lane >> 5;

    // ---- A fragments: row c, k = t*16 + hi*8 + j; hi+lo split (A exact) ----
    const float* rp = (c < SS) ? (out + OFF_HC + ((size_t)b * SS + c) * DD)
                    : (c == 20) ? (out + OFF_HU + (size_t)b * DD)
                    : (c == 21) ? (pred_w + 2 * DD) : nullptr;
    short8 aHi[4], aLo[4];
    #pragma unroll
    for (int t = 0; t < 4; ++t) {
        float v[8];
        if (rp) {
            const float4* p4 = (const float4*)(rp + t * 16 + hi * 8);
            float4 x = p4[0], y = p4[1];
            v[0]=x.x; v[1]=x.y; v[2]=x.z; v[3]=x.w;
            v[4]=y.x; v[5]=y.y; v[6]=y.z; v[7]=y.w;
        } else {
            #pragma unroll
            for (int j = 0; j < 8; ++j) v[j] = 0.f;
        }
        short8 h, lo;
        #pragma unroll
        for (int j = 0; j < 8; ++j) {
            unsigned short hb = f2bf(v[j]);
            h[j]  = (short)hb;
            lo[j] = (short)f2bf(v[j] - bf2f(hb));
        }
        aHi[t] = h; aLo[t] = lo;
    }

    // per-lane hcwc for the 12 C-regs holding score rows; c0 (uniform)
    float hcr[12];
    #pragma unroll
    for (int r = 0; r < 12; ++r) {
        int row = (r & 3) + 8 * (r >> 2) + 4 * hi;
        hcr[r] = hcwc_ws[b * 32 + row];
    }
    const float c0v = hcwc_ws[b * 32 + 24];

    #pragma unroll
    for (int T = 0; T < 2; ++T) {
        const int n0t = n0 + T * 32;
        const int idx = items[b * NN + n0t + c];
        const float* brow = item_emb + (size_t)idx * DD + hi * 8;

        short8 bf[4];
        #pragma unroll
        for (int t = 0; t < 4; ++t) {
            const float4* p4 = (const float4*)(brow + t * 16);
            bf[t] = pack8(p4[0], p4[1]);
        }

        f32x16 acc = {0.f,0.f,0.f,0.f,0.f,0.f,0.f,0.f,0.f,0.f,0.f,0.f,0.f,0.f,0.f,0.f};
        #pragma unroll
        for (int t = 0; t < 4; ++t) {
            acc = __builtin_amdgcn_mfma_f32_32x32x16_bf16(aHi[t], bf[t], acc, 0, 0, 0);
            acc = __builtin_amdgcn_mfma_f32_32x32x16_bf16(aLo[t], bf[t], acc, 0, 0, 0);
        }

        // rows 20 (huv) / 21 (vwv): regs 8/9 on the hi half
        const float huv = __shfl(acc[8], 32 + c);
        const float vwv = __shfl(acc[9], 32 + c);
        const float gb  = c0v + vwv;

        float* sc = out + OFF_SCORES + (size_t)b * SS * NN + n0t + c;
        float* at = out + OFF_ATTN   + (size_t)b * SS * NN + n0t + c;

        #pragma unroll
        for (int r = 0; r < 12; ++r) {
            if (!(hi && r >= 8)) {                  // hi half: regs 8..11 = rows 20..23
                int row = (r & 3) + 8 * (r >> 2) + 4 * hi;
                float hcv  = acc[r];
                float g    = gb + hcr[r];
                float attn = 1.f / (1.f + __expf(-g));
                float scv  = hcv + attn * (huv - hcv);
                __builtin_nontemporal_store(scv,  sc + (size_t)row * NN);
                __builtin_nontemporal_store(attn, at + (size_t)row * NN);
            }
        }
    }
}

extern "C" void kernel_launch(void* const* d_in, const int* in_sizes, int n_in,
                              void* d_out, int out_size, void* d_ws, size_t ws_size,
                              hipStream_t stream) {
    const int*   user_ids  = (const int*)d_in[0];
    const int*   sess_item = (const int*)d_in[1];
    const int*   rcnt_item = (const int*)d_in[2];
    const int*   items     = (const int*)d_in[3];
    const float* item_emb  = (const float*)d_in[4];
    const float* user_emb  = (const float*)d_in[5];
    const float* user_emb2 = (const float*)d_in[6];
    const float* ue_w1     = (const float*)d_in[7];
    const float* ue_b1     = (const float*)d_in[8];
    const float* ue_w2     = (const float*)d_in[9];
    const float* ue_b2     = (const float*)d_in[10];
    const float* uenc_w    = (const float*)d_in[11];
    const float* uenc_b    = (const float*)d_in[12];
    const float* pred_w    = (const float*)d_in[13];
    const float* pred_b    = (const float*)d_in[14];
    float* out = (float*)d_out;
    float* hcwc_ws = (float*)d_ws;                  // 4 KB

    hipLaunchKernelGGL(prep_kernel, dim3(BB), dim3(256), 0, stream,
                       user_ids, sess_item, rcnt_item, item_emb, user_emb, user_emb2,
                       ue_w1, ue_b1, ue_w2, ue_b2, uenc_w, uenc_b, pred_w, pred_b,
                       out, hcwc_ws);

    const int nstrips = NN / 64;                    // 625
    hipLaunchKernelGGL(score_kernel, dim3((nstrips + 3) / 4, BB), dim3(256), 0, stream,
                       items, item_emb, pred_w, hcwc_ws, out);
}

// Round 9
// 104.769 us; speedup vs baseline: 1.9994x; 1.1780x over previous
//
#include <hip/hip_runtime.h>
#include <hip/hip_bf16.h>
#include <math.h>

#define BB 32
#define SS 20
#define LL 50
#define NN 40000
#define DD 64
#define TBL_ROWS 100001   // item_emb has NUM_ITEM+1 = 100001 rows

// Output layout (flat f32): scores (B,S,N) | hu (B,D) | hc (B,S,D) | attn (B,S,N)
#define OFF_SCORES 0
#define OFF_HU     (BB * SS * NN)                 // 25,600,000
#define OFF_HC     (OFF_HU + BB * DD)             // 25,602,048
#define OFF_ATTN   (OFF_HC + BB * SS * DD)        // 25,643,008

// d_ws layout: [0,4096) hcwc scalars (32 b x 32 f32); [4096, +12.8MB) bf16 table.
#define WS_TBL_OFF 4096
#define WS_NEEDED  ((size_t)WS_TBL_OFF + (size_t)TBL_ROWS * DD * 2)

typedef short  short8 __attribute__((ext_vector_type(8)));
typedef float  f32x16 __attribute__((ext_vector_type(16)));

__device__ __forceinline__ unsigned short f2bf(float x) {   // RNE f32->bf16 (cold paths)
    unsigned u = __float_as_uint(x);
    unsigned r = (u + 0x7fffu + ((u >> 16) & 1u)) >> 16;
    return (unsigned short)r;
}
__device__ __forceinline__ float bf2f(unsigned short h) {
    return __uint_as_float(((unsigned)h) << 16);
}
// v_cvt_pk_bf16_f32: 2 f32 -> 1 u32 (lo|hi), single instr (no builtin on gfx950)
__device__ __forceinline__ unsigned cvtpk(float lo, float hi) {
    unsigned r;
    asm("v_cvt_pk_bf16_f32 %0, %1, %2" : "=v"(r) : "v"(lo), "v"(hi));
    return r;
}
__device__ __forceinline__ short8 pack8_hw(float4 x, float4 y) {
    uint4 iv;
    iv.x = cvtpk(x.x, x.y); iv.y = cvtpk(x.z, x.w);
    iv.z = cvtpk(y.x, y.y); iv.w = cvtpk(y.z, y.w);
    return __builtin_bit_cast(short8, iv);
}

// ---------------------------------------------------------------------------
// Kernel C: item_emb f32 -> bf16 table in ws. One float4 -> uint2 per thread.
// ---------------------------------------------------------------------------
__global__ __launch_bounds__(256) void conv_kernel(
    const float* __restrict__ src, unsigned int* __restrict__ dst)
{
    const int i = blockIdx.x * 256 + threadIdx.x;
    if (i >= TBL_ROWS * 16) return;
    float4 v = ((const float4*)src)[i];
    ((uint2*)dst)[i] = make_uint2(cvtpk(v.x, v.y), cvtpk(v.z, v.w));
}

// ---------------------------------------------------------------------------
// Kernel A: per-batch prep. One block per b, 256 threads (4 waves).
// Computes hu, hc (f32, into out) and hcwc[20] + c0 scalars (into ws).
// ---------------------------------------------------------------------------
__global__ __launch_bounds__(256) void prep_kernel(
    const int* __restrict__ user_ids,
    const int* __restrict__ sess_item,
    const int* __restrict__ rcnt_item,
    const float* __restrict__ item_emb,
    const float* __restrict__ user_emb,
    const float* __restrict__ user_emb2,
    const float* __restrict__ ue_w1,
    const float* __restrict__ ue_b1,
    const float* __restrict__ ue_w2,
    const float* __restrict__ ue_b2,
    const float* __restrict__ uenc_w,
    const float* __restrict__ uenc_b,
    const float* __restrict__ pred_w,
    const float* __restrict__ pred_b,
    float* __restrict__ out,
    float* __restrict__ hcwc_ws)
{
    const int b    = blockIdx.x;
    const int tid  = threadIdx.x;
    const int lane = tid & 63;
    const int wv   = tid >> 6;

    __shared__ float uemb_s[DD];
    __shared__ float u2_s[DD];
    __shared__ float hs_s[LL][DD];
    __shared__ float wraw_s[LL];
    __shared__ float wn_s[LL];
    __shared__ float part_s[4][DD];
    __shared__ float hr_s[DD];
    __shared__ float e_s[SS][DD + 1];
    __shared__ float a_tmp[4][SS];
    __shared__ float hc_s[SS][DD];
    __shared__ float hu_s[DD];

    const int uid = user_ids[b];
    if (tid < DD) {
        uemb_s[tid] = user_emb[(size_t)uid * DD + tid];
        u2_s[tid]   = user_emb2[(size_t)uid * DD + tid];
    }
    for (int t = tid; t < LL * DD; t += 256) {
        int l = t >> 6, d = t & 63;
        int idx = rcnt_item[b * LL + l];
        hs_s[l][d] = item_emb[(size_t)idx * DD + d];
    }
    for (int t = tid; t < SS * DD; t += 256) {
        int s = t >> 6, d = t & 63;
        int idx = sess_item[b * SS + s];
        e_s[s][d] = item_emb[(size_t)idx * DD + d];
    }
    __syncthreads();

    float pu = 0.f;
    #pragma unroll 8
    for (int i = 0; i < DD; ++i) pu += uemb_s[i] * ue_w1[i * DD + lane];
    const float b1j = ue_b1[lane];
    const float w2j = ue_w2[lane];
    const float b2  = ue_b2[0];
    for (int l = wv; l < LL; l += 4) {
        float acc = pu + b1j;
        #pragma unroll 8
        for (int i = 0; i < DD; ++i) acc += hs_s[l][i] * ue_w1[(DD + i) * DD + lane];
        acc = fmaxf(acc, 0.f);
        float contrib = acc * w2j;
        #pragma unroll
        for (int off = 32; off; off >>= 1) contrib += __shfl_xor(contrib, off);
        if (lane == 0) wraw_s[l] = contrib + b2;
    }
    __syncthreads();

    if (wv == 0) {
        float x = (lane < LL) ? wraw_s[lane] : -INFINITY;
        float m = x;
        #pragma unroll
        for (int off = 32; off; off >>= 1) m = fmaxf(m, __shfl_xor(m, off));
        float maskl = (lane < LL && rcnt_item[b * LL + lane] != 0) ? 1.f : 0.f;
        float e = (lane < LL) ? (__expf(x - m) + 1e-10f) * maskl : 0.f;
        float sum = e;
        #pragma unroll
        for (int off = 32; off; off >>= 1) sum += __shfl_xor(sum, off);
        if (lane < LL) wn_s[lane] = e / sum;
    }
    __syncthreads();

    {
        float p = 0.f;
        for (int l = wv; l < LL; l += 4) p += wn_s[l] * hs_s[l][lane];
        part_s[wv][lane] = p;
    }
    __syncthreads();
    if (wv == 0) hr_s[lane] = part_s[0][lane] + part_s[1][lane] + part_s[2][lane] + part_s[3][lane];
    __syncthreads();

    {
        float p = 0.f;
        for (int i = wv * 32; i < wv * 32 + 32; ++i) {
            float c = (i < DD) ? u2_s[i] : hr_s[i - DD];
            p += c * uenc_w[i * DD + lane];
        }
        part_s[wv][lane] = p;
    }
    __syncthreads();
    if (wv == 0) {
        float hu = uenc_b[lane] + part_s[0][lane] + part_s[1][lane] + part_s[2][lane] + part_s[3][lane];
        hu_s[lane] = hu;
        out[OFF_HU + b * DD + lane] = hu;
    }
    __syncthreads();

    for (int s = wv; s < SS; s += 4) {
        const int t = lane;
        float lt = -INFINITY;
        float maskt = 0.f;
        if (t < SS) {
            float dot = 0.f;
            #pragma unroll 8
            for (int d = 0; d < DD; ++d) dot += e_s[s][d] * e_s[t][d];
            lt = dot * 0.125f;
            maskt = (sess_item[b * SS + t] != 0) ? 1.f : 0.f;
        }
        float srow = (sess_item[b * SS + s] != 0) ? 1.f : 0.f;
        float m = lt;
        #pragma unroll
        for (int off = 32; off; off >>= 1) m = fmaxf(m, __shfl_xor(m, off));
        float e = (t < SS) ? (__expf(lt - m) + 1e-10f) * (maskt * srow) : 0.f;
        float sum = e;
        #pragma unroll
        for (int off = 32; off; off >>= 1) sum += __shfl_xor(sum, off);
        if (t < SS) a_tmp[wv][t] = e / sum;
        __syncthreads();
        float hc = 0.f;
        #pragma unroll
        for (int tt = 0; tt < SS; ++tt) hc += a_tmp[wv][tt] * e_s[tt][lane];
        hc_s[s][lane] = hc;
        out[OFF_HC + (size_t)(b * SS + s) * DD + lane] = hc;
        __syncthreads();
    }

    // ---- scalars for score kernel ----
    for (int s = wv; s < SS; s += 4) {                 // hcwc[s] = hc[s].wc
        float p = hc_s[s][lane] * pred_w[DD + lane];
        #pragma unroll
        for (int off = 32; off; off >>= 1) p += __shfl_xor(p, off);
        if (lane == 0) hcwc_ws[b * 32 + s] = p;
    }
    if (wv == 1) {                                      // c0 -> slot 24
        float p = hu_s[lane] * pred_w[lane];
        #pragma unroll
        for (int off = 32; off; off >>= 1) p += __shfl_xor(p, off);
        if (lane == 0) hcwc_ws[b * 32 + 24] = p + pred_b[0];
    }
    if (tid < 11) {                                     // zero 20..23, 25..31
        int sl = (tid < 4) ? (20 + tid) : (21 + tid);
        hcwc_ws[b * 32 + sl] = 0.f;
    }
}

// ---------------------------------------------------------------------------
// Kernel B (MFMA): barrier-free, LDS-free. Wave = 64-col strip of one batch,
// 2 tiles of 32 cols. G[32x32] = comb . vemb^T via mfma_f32_32x32x16_bf16,
// K=64 (4 k-steps, hi+lo A split -> 8 MFMA/tile, A exact).
// USE_TBL: B-frags are direct short8 loads from the pre-converted bf16 table
// (no conversion in hot loop, half the gather bytes). Else: f32 + cvt_pk.
// C layout: col=lane&31, row=(reg&3)+8*(reg>>2)+4*(lane>>5). G rows 20/21 =
// huv/vwv (regs 8/9, hi half), redistributed by one __shfl each.
// ---------------------------------------------------------------------------
template<bool USE_TBL>
__global__ __launch_bounds__(256) void score_kernel(
    const int* __restrict__ items,
    const float* __restrict__ item_emb,
    const unsigned short* __restrict__ tbl,
    const float* __restrict__ pred_w,
    const float* __restrict__ hcwc_ws,
    float* __restrict__ out)
{
    const int tid   = threadIdx.x;
    const int lane  = tid & 63;
    const int wv    = tid >> 6;
    const int b     = blockIdx.y;
    const int strip = blockIdx.x * 4 + wv;          // 64-column strip
    if (strip >= NN / 64) return;                   // wave-uniform exit
    const int n0 = strip * 64;
    const int c  = lane & 31;
    const int hi = lane >> 5;

    // ---- A fragments: row c, k = t*16 + hi*8 + j; hi+lo split (A exact) ----
    const float* rp = (c < SS) ? (out + OFF_HC + ((size_t)b * SS + c) * DD)
                    : (c == 20) ? (out + OFF_HU + (size_t)b * DD)
                    : (c == 21) ? (pred_w + 2 * DD) : nullptr;
    short8 aHi[4], aLo[4];
    #pragma unroll
    for (int t = 0; t < 4; ++t) {
        float v[8];
        if (rp) {
            const float4* p4 = (const float4*)(rp + t * 16 + hi * 8);
            float4 x = p4[0], y = p4[1];
            v[0]=x.x; v[1]=x.y; v[2]=x.z; v[3]=x.w;
            v[4]=y.x; v[5]=y.y; v[6]=y.z; v[7]=y.w;
        } else {
            #pragma unroll
            for (int j = 0; j < 8; ++j) v[j] = 0.f;
        }
        short8 h, lo;
        #pragma unroll
        for (int j = 0; j < 8; ++j) {
            unsigned short hb = f2bf(v[j]);
            h[j]  = (short)hb;
            lo[j] = (short)f2bf(v[j] - bf2f(hb));
        }
        aHi[t] = h; aLo[t] = lo;
    }

    // per-lane hcwc for the 12 C-regs holding score rows; c0 (uniform)
    float hcr[12];
    #pragma unroll
    for (int r = 0; r < 12; ++r) {
        int row = (r & 3) + 8 * (r >> 2) + 4 * hi;
        hcr[r] = hcwc_ws[b * 32 + row];
    }
    const float c0v = hcwc_ws[b * 32 + 24];

    int idxT[2];
    idxT[0] = items[b * NN + n0 + c];
    idxT[1] = items[b * NN + n0 + 32 + c];

    #pragma unroll
    for (int T = 0; T < 2; ++T) {
        const int n0t = n0 + T * 32;
        const int idx = idxT[T];

        short8 bf[4];
        if (USE_TBL) {
            const unsigned short* brow = tbl + (size_t)idx * DD + hi * 8;
            #pragma unroll
            for (int t = 0; t < 4; ++t) bf[t] = *(const short8*)(brow + t * 16);
        } else {
            const float* brow = item_emb + (size_t)idx * DD + hi * 8;
            #pragma unroll
            for (int t = 0; t < 4; ++t) {
                const float4* p4 = (const float4*)(brow + t * 16);
                bf[t] = pack8_hw(p4[0], p4[1]);
            }
        }

        f32x16 acc = {0.f,0.f,0.f,0.f,0.f,0.f,0.f,0.f,0.f,0.f,0.f,0.f,0.f,0.f,0.f,0.f};
        #pragma unroll
        for (int t = 0; t < 4; ++t) {
            acc = __builtin_amdgcn_mfma_f32_32x32x16_bf16(aHi[t], bf[t], acc, 0, 0, 0);
            acc = __builtin_amdgcn_mfma_f32_32x32x16_bf16(aLo[t], bf[t], acc, 0, 0, 0);
        }

        // rows 20 (huv) / 21 (vwv): regs 8/9 on the hi half
        const float huv = __shfl(acc[8], 32 + c);
        const float vwv = __shfl(acc[9], 32 + c);
        const float gb  = c0v + vwv;

        float* sc = out + OFF_SCORES + (size_t)b * SS * NN + n0t + c;
        float* at = out + OFF_ATTN   + (size_t)b * SS * NN + n0t + c;

        #pragma unroll
        for (int r = 0; r < 12; ++r) {
            if (!(hi && r >= 8)) {                  // hi half: regs 8..11 = rows 20..23
                int row = (r & 3) + 8 * (r >> 2) + 4 * hi;
                float hcv  = acc[r];
                float g    = gb + hcr[r];
                float attn = 1.f / (1.f + __expf(-g));
                float scv  = hcv + attn * (huv - hcv);
                __builtin_nontemporal_store(scv,  sc + (size_t)row * NN);
                __builtin_nontemporal_store(attn, at + (size_t)row * NN);
            }
        }
    }
}

extern "C" void kernel_launch(void* const* d_in, const int* in_sizes, int n_in,
                              void* d_out, int out_size, void* d_ws, size_t ws_size,
                              hipStream_t stream) {
    const int*   user_ids  = (const int*)d_in[0];
    const int*   sess_item = (const int*)d_in[1];
    const int*   rcnt_item = (const int*)d_in[2];
    const int*   items     = (const int*)d_in[3];
    const float* item_emb  = (const float*)d_in[4];
    const float* user_emb  = (const float*)d_in[5];
    const float* user_emb2 = (const float*)d_in[6];
    const float* ue_w1     = (const float*)d_in[7];
    const float* ue_b1     = (const float*)d_in[8];
    const float* ue_w2     = (const float*)d_in[9];
    const float* ue_b2     = (const float*)d_in[10];
    const float* uenc_w    = (const float*)d_in[11];
    const float* uenc_b    = (const float*)d_in[12];
    const float* pred_w    = (const float*)d_in[13];
    const float* pred_b    = (const float*)d_in[14];
    float* out = (float*)d_out;

    float*          hcwc_ws = (float*)d_ws;
    unsigned short* tbl     = (unsigned short*)((char*)d_ws + WS_TBL_OFF);
    const bool use_tbl = (ws_size >= WS_NEEDED);

    if (use_tbl) {
        const int nconv = TBL_ROWS * 16;            // float4 groups
        hipLaunchKernelGGL(conv_kernel, dim3((nconv + 255) / 256), dim3(256), 0, stream,
                           item_emb, (unsigned int*)tbl);
    }

    hipLaunchKernelGGL(prep_kernel, dim3(BB), dim3(256), 0, stream,
                       user_ids, sess_item, rcnt_item, item_emb, user_emb, user_emb2,
                       ue_w1, ue_b1, ue_w2, ue_b2, uenc_w, uenc_b, pred_w, pred_b,
                       out, hcwc_ws);

    const int nstrips = NN / 64;                    // 625
    const dim3 grid((nstrips + 3) / 4, BB);
    if (use_tbl) {
        hipLaunchKernelGGL((score_kernel<true>), grid, dim3(256), 0, stream,
                           items, item_emb, tbl, pred_w, hcwc_ws, out);
    } else {
        hipLaunchKernelGGL((score_kernel<false>), grid, dim3(256), 0, stream,
                           items, item_emb, tbl, pred_w, hcwc_ws, out);
    }
}

// Round 10
// 104.687 us; speedup vs baseline: 2.0009x; 1.0008x over previous
//
#include <hip/hip_runtime.h>
#include <hip/hip_bf16.h>
#include <math.h>

#define BB 32
#define SS 20
#define LL 50
#define NN 40000
#define DD 64
#define TBL_ROWS 100001   // item_emb rows = NUM_ITEM+1

// Output layout (flat f32): scores (B,S,N) | hu (B,D) | hc (B,S,D) | attn (B,S,N)
#define OFF_SCORES 0
#define OFF_HU     (BB * SS * NN)
#define OFF_HC     (OFF_HU + BB * DD)
#define OFF_ATTN   (OFF_HC + BB * SS * DD)

// d_ws layout: [0,4096) hcwc (32b x 32 f32) | [4096,+128K) comb bf16 (32b x 32rows x 64)
//              | [135168, +12.8MB) bf16 item table
#define WS_COMB_OFF 4096
#define WS_TBL_OFF  (WS_COMB_OFF + BB * 32 * DD * 2)          // 135168
#define WS_NEEDED   ((size_t)WS_TBL_OFF + (size_t)TBL_ROWS * DD * 2)
#define CONV_BLOCKS ((TBL_ROWS * 16 + 255) / 256)             // 6251

typedef short  short8 __attribute__((ext_vector_type(8)));
typedef float  f32x16 __attribute__((ext_vector_type(16)));

__device__ __forceinline__ unsigned short f2bf(float x) {   // RNE f32->bf16 (cold)
    unsigned u = __float_as_uint(x);
    return (unsigned short)((u + 0x7fffu + ((u >> 16) & 1u)) >> 16);
}
// v_cvt_pk_bf16_f32: 2 f32 -> 1 u32, single instr
__device__ __forceinline__ unsigned cvtpk(float lo, float hi) {
    unsigned r;
    asm("v_cvt_pk_bf16_f32 %0, %1, %2" : "=v"(r) : "v"(lo), "v"(hi));
    return r;
}
__device__ __forceinline__ short8 pack8_hw(float4 x, float4 y) {
    uint4 iv;
    iv.x = cvtpk(x.x, x.y); iv.y = cvtpk(x.z, x.w);
    iv.z = cvtpk(y.x, y.y); iv.w = cvtpk(y.z, y.w);
    return __builtin_bit_cast(short8, iv);
}

// ---------------------------------------------------------------------------
// Fused setup: blocks [0, convBlocks) convert item_emb->bf16 table; blocks
// [convBlocks, +32) run per-batch prep. Overlaps the two on one launch.
// ---------------------------------------------------------------------------
__global__ __launch_bounds__(256) void setup_kernel(
    const int* __restrict__ user_ids,
    const int* __restrict__ sess_item,
    const int* __restrict__ rcnt_item,
    const float* __restrict__ item_emb,
    const float* __restrict__ user_emb,
    const float* __restrict__ user_emb2,
    const float* __restrict__ ue_w1,
    const float* __restrict__ ue_b1,
    const float* __restrict__ ue_w2,
    const float* __restrict__ ue_b2,
    const float* __restrict__ uenc_w,
    const float* __restrict__ uenc_b,
    const float* __restrict__ pred_w,
    const float* __restrict__ pred_b,
    float* __restrict__ out,
    float* __restrict__ hcwc_ws,
    unsigned short* __restrict__ comb_bf,
    unsigned int* __restrict__ tbl_dst,
    int convBlocks, int has_comb)
{
    const int tid  = threadIdx.x;

    // ---- conv part ----
    if (blockIdx.x < (unsigned)convBlocks) {
        const int i = blockIdx.x * 256 + tid;
        if (i < TBL_ROWS * 16) {
            float4 v = ((const float4*)item_emb)[i];
            ((uint2*)tbl_dst)[i] = make_uint2(cvtpk(v.x, v.y), cvtpk(v.z, v.w));
        }
        return;
    }

    // ---- prep part ----
    const int b    = blockIdx.x - convBlocks;
    const int lane = tid & 63;
    const int wv   = tid >> 6;

    __shared__ float uemb_s[DD];
    __shared__ float u2_s[DD];
    __shared__ float hs_s[LL][DD];
    __shared__ float wraw_s[LL];
    __shared__ float wn_s[LL];
    __shared__ float part_s[4][DD];
    __shared__ float hr_s[DD];
    __shared__ float e_s[SS][DD + 1];
    __shared__ float a_tmp[4][SS];
    __shared__ float hc_s[SS][DD];
    __shared__ float hu_s[DD];

    const int uid = user_ids[b];
    if (tid < DD) {
        uemb_s[tid] = user_emb[(size_t)uid * DD + tid];
        u2_s[tid]   = user_emb2[(size_t)uid * DD + tid];
    }
    for (int t = tid; t < LL * DD; t += 256) {
        int l = t >> 6, d = t & 63;
        int idx = rcnt_item[b * LL + l];
        hs_s[l][d] = item_emb[(size_t)idx * DD + d];
    }
    for (int t = tid; t < SS * DD; t += 256) {
        int s = t >> 6, d = t & 63;
        int idx = sess_item[b * SS + s];
        e_s[s][d] = item_emb[(size_t)idx * DD + d];
    }
    __syncthreads();

    // phase 2: attention MLP logits
    float pu = 0.f;
    #pragma unroll 8
    for (int i = 0; i < DD; ++i) pu += uemb_s[i] * ue_w1[i * DD + lane];
    const float b1j = ue_b1[lane];
    const float w2j = ue_w2[lane];
    const float b2  = ue_b2[0];
    for (int l = wv; l < LL; l += 4) {
        float acc = pu + b1j;
        #pragma unroll 8
        for (int i = 0; i < DD; ++i) acc += hs_s[l][i] * ue_w1[(DD + i) * DD + lane];
        acc = fmaxf(acc, 0.f);
        float contrib = acc * w2j;
        #pragma unroll
        for (int off = 32; off; off >>= 1) contrib += __shfl_xor(contrib, off);
        if (lane == 0) wraw_s[l] = contrib + b2;
    }
    __syncthreads();

    // phase 3: masked softmax over L
    if (wv == 0) {
        float x = (lane < LL) ? wraw_s[lane] : -INFINITY;
        float m = x;
        #pragma unroll
        for (int off = 32; off; off >>= 1) m = fmaxf(m, __shfl_xor(m, off));
        float maskl = (lane < LL && rcnt_item[b * LL + lane] != 0) ? 1.f : 0.f;
        float e = (lane < LL) ? (__expf(x - m) + 1e-10f) * maskl : 0.f;
        float sum = e;
        #pragma unroll
        for (int off = 32; off; off >>= 1) sum += __shfl_xor(sum, off);
        if (lane < LL) wn_s[lane] = e / sum;
    }
    __syncthreads();

    // phase 4: hr
    {
        float p = 0.f;
        for (int l = wv; l < LL; l += 4) p += wn_s[l] * hs_s[l][lane];
        part_s[wv][lane] = p;
    }
    __syncthreads();
    if (wv == 0) hr_s[lane] = part_s[0][lane] + part_s[1][lane] + part_s[2][lane] + part_s[3][lane];
    __syncthreads();

    // phase 5: hu
    {
        float p = 0.f;
        for (int i = wv * 32; i < wv * 32 + 32; ++i) {
            float c = (i < DD) ? u2_s[i] : hr_s[i - DD];
            p += c * uenc_w[i * DD + lane];
        }
        part_s[wv][lane] = p;
    }
    __syncthreads();
    if (wv == 0) {
        float hu = uenc_b[lane] + part_s[0][lane] + part_s[1][lane] + part_s[2][lane] + part_s[3][lane];
        hu_s[lane] = hu;
        out[OFF_HU + b * DD + lane] = hu;
    }
    __syncthreads();

    // phase 6: session self-attention -> hc. a_tmp[wv] is WAVE-LOCAL: no
    // block barriers needed inside the loop (same-wave LDS RAW is
    // lgkmcnt-ordered; LDS ops retire in issue order per wave).
    for (int s = wv; s < SS; s += 4) {
        const int t = lane;
        float lt = -INFINITY;
        float maskt = 0.f;
        if (t < SS) {
            float dot = 0.f;
            #pragma unroll 8
            for (int d = 0; d < DD; ++d) dot += e_s[s][d] * e_s[t][d];
            lt = dot * 0.125f;
            maskt = (sess_item[b * SS + t] != 0) ? 1.f : 0.f;
        }
        float srow = (sess_item[b * SS + s] != 0) ? 1.f : 0.f;
        float m = lt;
        #pragma unroll
        for (int off = 32; off; off >>= 1) m = fmaxf(m, __shfl_xor(m, off));
        float e = (t < SS) ? (__expf(lt - m) + 1e-10f) * (maskt * srow) : 0.f;
        float sum = e;
        #pragma unroll
        for (int off = 32; off; off >>= 1) sum += __shfl_xor(sum, off);
        if (t < SS) a_tmp[wv][t] = e / sum;
        float hc = 0.f;
        #pragma unroll
        for (int tt = 0; tt < SS; ++tt) hc += a_tmp[wv][tt] * e_s[tt][lane];
        hc_s[s][lane] = hc;
        out[OFF_HC + (size_t)(b * SS + s) * DD + lane] = hc;
    }
    __syncthreads();   // hc_s complete across waves before phase 7

    // phase 7: score-kernel operands
    for (int s = wv; s < SS; s += 4) {                 // hcwc[s] = hc[s].wc
        float p = hc_s[s][lane] * pred_w[DD + lane];
        #pragma unroll
        for (int off = 32; off; off >>= 1) p += __shfl_xor(p, off);
        if (lane == 0) hcwc_ws[b * 32 + s] = p;
    }
    if (wv == 1) {                                      // c0 -> slot 24
        float p = hu_s[lane] * pred_w[lane];
        #pragma unroll
        for (int off = 32; off; off >>= 1) p += __shfl_xor(p, off);
        if (lane == 0) hcwc_ws[b * 32 + 24] = p + pred_b[0];
    }
    if (tid < 11) {
        int sl = (tid < 4) ? (20 + tid) : (21 + tid);   // 20..23, 25..31
        hcwc_ws[b * 32 + sl] = 0.f;
    }
    if (has_comb) {                                     // comb bf16 rows
        for (int t = tid; t < 32 * DD; t += 256) {
            int row = t >> 6, d = t & 63;
            float v = (row < SS) ? hc_s[row][d]
                    : (row == 20) ? hu_s[d]
                    : (row == 21) ? pred_w[2 * DD + d] : 0.f;
            comb_bf[b * (32 * DD) + t] = f2bf(v);
        }
    }
}

// ---------------------------------------------------------------------------
// Score (MFMA): barrier-free, LDS-free. Wave = 128-col strip (4 tiles of 32),
// ping-pong B prefetch (tile T+1 gathers issued before tile T's MFMA).
// G[32x32] = comb . vemb^T via 4x mfma_f32_32x32x16_bf16 (K=64, single-
// rounded bf16 A -- absmax floor is the harness's 0.0039, threshold 0.0102).
// C layout: col=lane&31, row=(reg&3)+8*(reg>>2)+4*(lane>>5). G rows 20/21 =
// huv/vwv (regs 8/9, hi half). Stores: 512 B/row/wave contiguous across T.
// ---------------------------------------------------------------------------
#define LOADB_TBL(dst, idx)                                              \
    {                                                                    \
        const unsigned short* brow_ = tbl + (size_t)(idx) * DD + hi * 8; \
        dst[0] = *(const short8*)(brow_ +  0);                           \
        dst[1] = *(const short8*)(brow_ + 16);                           \
        dst[2] = *(const short8*)(brow_ + 32);                           \
        dst[3] = *(const short8*)(brow_ + 48);                           \
    }
#define LOADB_F32(dst, idx)                                              \
    {                                                                    \
        const float* brow_ = item_emb + (size_t)(idx) * DD + hi * 8;     \
        const float4* p0_ = (const float4*)(brow_ +  0);                 \
        const float4* p1_ = (const float4*)(brow_ + 16);                 \
        const float4* p2_ = (const float4*)(brow_ + 32);                 \
        const float4* p3_ = (const float4*)(brow_ + 48);                 \
        dst[0] = pack8_hw(p0_[0], p0_[1]);                               \
        dst[1] = pack8_hw(p1_[0], p1_[1]);                               \
        dst[2] = pack8_hw(p2_[0], p2_[1]);                               \
        dst[3] = pack8_hw(p3_[0], p3_[1]);                               \
    }

template<bool USE_TBL>
__global__ __launch_bounds__(256) void score_kernel(
    const int* __restrict__ items,
    const float* __restrict__ item_emb,
    const unsigned short* __restrict__ tbl,
    const unsigned short* __restrict__ comb_bf,
    const float* __restrict__ pred_w,
    const float* __restrict__ hcwc_ws,
    float* __restrict__ out)
{
    const int tid   = threadIdx.x;
    const int lane  = tid & 63;
    const int wv    = tid >> 6;
    const int b     = blockIdx.y;
    const int strip = blockIdx.x * 4 + wv;          // 128-col strip
    const int n0    = strip * 128;
    if (n0 >= NN) return;                           // wave-uniform exit
    const int c  = lane & 31;
    const int hi = lane >> 5;

    // ---- A fragments: row c, k = t*16 + hi*8 + j ----
    short8 aHi[4];
    if (USE_TBL) {
        const unsigned short* arow = comb_bf + b * (32 * DD) + c * DD + hi * 8;
        #pragma unroll
        for (int t = 0; t < 4; ++t) aHi[t] = *(const short8*)(arow + t * 16);
    } else {
        const float* rp = (c < SS) ? (out + OFF_HC + ((size_t)b * SS + c) * DD)
                        : (c == 20) ? (out + OFF_HU + (size_t)b * DD)
                        : (c == 21) ? (pred_w + 2 * DD) : nullptr;
        #pragma unroll
        for (int t = 0; t < 4; ++t) {
            if (rp) {
                const float4* p4 = (const float4*)(rp + t * 16 + hi * 8);
                aHi[t] = pack8_hw(p4[0], p4[1]);
            } else {
                uint4 z = make_uint4(0, 0, 0, 0);
                aHi[t] = __builtin_bit_cast(short8, z);
            }
        }
    }

    // per-lane hcwc for the 12 C-regs holding score rows; c0 (uniform)
    float hcr[12];
    #pragma unroll
    for (int r = 0; r < 12; ++r) {
        int row = (r & 3) + 8 * (r >> 2) + 4 * hi;
        hcr[r] = hcwc_ws[b * 32 + row];
    }
    const float c0v = hcwc_ws[b * 32 + 24];

    int idxT[4];
    #pragma unroll
    for (int T = 0; T < 4; ++T) {
        int nt = n0 + T * 32;
        idxT[T] = (nt < NN) ? items[b * NN + nt + c] : 0;
    }

    short8 bfA[4], bfB[4];
    if (USE_TBL) { LOADB_TBL(bfA, idxT[0]); } else { LOADB_F32(bfA, idxT[0]); }

    #pragma unroll
    for (int T = 0; T < 4; ++T) {
        const int n0t = n0 + T * 32;
        // prefetch next tile into the other buffer (static after full unroll)
        if (T + 1 < 4 && n0 + (T + 1) * 32 < NN) {
            if ((T & 1) == 0) {
                if (USE_TBL) { LOADB_TBL(bfB, idxT[T + 1]); } else { LOADB_F32(bfB, idxT[T + 1]); }
            } else {
                if (USE_TBL) { LOADB_TBL(bfA, idxT[T + 1]); } else { LOADB_F32(bfA, idxT[T + 1]); }
            }
        }
        if (n0t >= NN) continue;

        f32x16 acc = {0.f,0.f,0.f,0.f,0.f,0.f,0.f,0.f,0.f,0.f,0.f,0.f,0.f,0.f,0.f,0.f};
        if ((T & 1) == 0) {
            #pragma unroll
            for (int t = 0; t < 4; ++t)
                acc = __builtin_amdgcn_mfma_f32_32x32x16_bf16(aHi[t], bfA[t], acc, 0, 0, 0);
        } else {
            #pragma unroll
            for (int t = 0; t < 4; ++t)
                acc = __builtin_amdgcn_mfma_f32_32x32x16_bf16(aHi[t], bfB[t], acc, 0, 0, 0);
        }

        const float huv = __shfl(acc[8], 32 + c);
        const float vwv = __shfl(acc[9], 32 + c);
        const float gb  = c0v + vwv;

        float* sc = out + OFF_SCORES + (size_t)b * SS * NN + n0t + c;
        float* at = out + OFF_ATTN   + (size_t)b * SS * NN + n0t + c;

        #pragma unroll
        for (int r = 0; r < 12; ++r) {
            if (!(hi && r >= 8)) {                  // hi half: regs 8..11 = rows 20..23
                int row = (r & 3) + 8 * (r >> 2) + 4 * hi;
                float hcv  = acc[r];
                float g    = gb + hcr[r];
                float attn = 1.f / (1.f + __expf(-g));
                float scv  = hcv + attn * (huv - hcv);
                __builtin_nontemporal_store(scv,  sc + (size_t)row * NN);
                __builtin_nontemporal_store(attn, at + (size_t)row * NN);
            }
        }
    }
}

extern "C" void kernel_launch(void* const* d_in, const int* in_sizes, int n_in,
                              void* d_out, int out_size, void* d_ws, size_t ws_size,
                              hipStream_t stream) {
    const int*   user_ids  = (const int*)d_in[0];
    const int*   sess_item = (const int*)d_in[1];
    const int*   rcnt_item = (const int*)d_in[2];
    const int*   items     = (const int*)d_in[3];
    const float* item_emb  = (const float*)d_in[4];
    const float* user_emb  = (const float*)d_in[5];
    const float* user_emb2 = (const float*)d_in[6];
    const float* ue_w1     = (const float*)d_in[7];
    const float* ue_b1     = (const float*)d_in[8];
    const float* ue_w2     = (const float*)d_in[9];
    const float* ue_b2     = (const float*)d_in[10];
    const float* uenc_w    = (const float*)d_in[11];
    const float* uenc_b    = (const float*)d_in[12];
    const float* pred_w    = (const float*)d_in[13];
    const float* pred_b    = (const float*)d_in[14];
    float* out = (float*)d_out;

    float*          hcwc_ws = (float*)d_ws;
    unsigned short* comb_bf = (unsigned short*)((char*)d_ws + WS_COMB_OFF);
    unsigned short* tbl     = (unsigned short*)((char*)d_ws + WS_TBL_OFF);
    const bool use_tbl = (ws_size >= WS_NEEDED);
    const int  convB   = use_tbl ? CONV_BLOCKS : 0;

    hipLaunchKernelGGL(setup_kernel, dim3(convB + BB), dim3(256), 0, stream,
                       user_ids, sess_item, rcnt_item, item_emb, user_emb, user_emb2,
                       ue_w1, ue_b1, ue_w2, ue_b2, uenc_w, uenc_b, pred_w, pred_b,
                       out, hcwc_ws, comb_bf, (unsigned int*)tbl,
                       convB, use_tbl ? 1 : 0);

    const int nstrips = (NN + 127) / 128;           // 313
    const dim3 grid((nstrips + 3) / 4, BB);         // 79 x 32
    if (use_tbl) {
        hipLaunchKernelGGL((score_kernel<true>), grid, dim3(256), 0, stream,
                           items, item_emb, tbl, comb_bf, pred_w, hcwc_ws, out);
    } else {
        hipLaunchKernelGGL((score_kernel<false>), grid, dim3(256), 0, stream,
                           items, item_emb, tbl, comb_bf, pred_w, hcwc_ws, out);
    }
}